// Round 1
// baseline (1005.448 us; speedup 1.0000x reference)
//
#include <hip/hip_runtime.h>
#include <hip/hip_fp16.h>

// GCNRegressor: 3x GCNConv(128->128) + mean-pool + 2-layer MLP head.
// CSR-by-dst bucket sort; MFMA fp16 GEMM with register-resident B; T in
// EIGHT 16-feature slices (3.2 MB/slice -> fits a 4 MB per-XCD L2); agg
// runs 8 passes with pass = blockIdx%8 so (under round-robin block->XCD
// dispatch) XCD p exclusively gathers slice p from its own L2. csr_src /
// out use non-temporal ops so the stream does not evict the slice.
// fused mean-pool + MLP head. f32 accumulate everywhere.

#define HID 128
#define NGR 512
#define NB_SHIFT 9
#define NB_W 512
#define EPB 4096

typedef __attribute__((ext_vector_type(8))) _Float16 half8;
typedef __attribute__((ext_vector_type(4))) float floatx4;

// ---------------- graph prep: bucket sort by destination ----------------

__global__ __launch_bounds__(256) void k_hist(const int* __restrict__ col,
                                              int* __restrict__ ghist, int E, int nb) {
    __shared__ int h[256];
    h[threadIdx.x] = 0;
    __syncthreads();
    for (int e = blockIdx.x * 256 + threadIdx.x; e < E; e += gridDim.x * 256)
        atomicAdd(&h[col[e] >> NB_SHIFT], 1);
    __syncthreads();
    int t = threadIdx.x;
    if (t < nb && h[t]) atomicAdd(&ghist[t], h[t]);
}

__global__ __launch_bounds__(256) void k_bscan(const int* __restrict__ ghist,
                                               int* __restrict__ bbase,
                                               int* __restrict__ rowptr,
                                               int N, int E, int nb) {
    __shared__ int wsum[4];
    int t = threadIdx.x, lane = t & 63, wid = t >> 6;
    int v = (t < nb) ? ghist[t] : 0;
    int sc = v;
    #pragma unroll
    for (int off = 1; off < 64; off <<= 1) {
        int u = __shfl_up(sc, off);
        if (lane >= off) sc += u;
    }
    if (lane == 63) wsum[wid] = sc;
    __syncthreads();
    int offs = 0;
    for (int w = 0; w < wid; w++) offs += wsum[w];
    int excl = offs + sc - v;
    if (t <= nb) bbase[t] = excl;
    if (t == 0) rowptr[N] = E;
}

// packed entry: (src << 9) | (dst & 511)
__global__ __launch_bounds__(512) void k_scatter(const int* __restrict__ row,
                                                 const int* __restrict__ col,
                                                 const int* __restrict__ bbase,
                                                 int* __restrict__ bcur,
                                                 unsigned* __restrict__ sorted, int E) {
    __shared__ int hist[256];
    __shared__ int cur[256];
    int t = threadIdx.x;
    if (t < 256) hist[t] = 0;
    __syncthreads();
    int base = blockIdx.x * EPB;
    #pragma unroll
    for (int i = 0; i < EPB / 512; i++) {
        int e = base + i * 512 + t;
        if (e < E) atomicAdd(&hist[col[e] >> NB_SHIFT], 1);
    }
    __syncthreads();
    if (t < 256 && hist[t] > 0) cur[t] = atomicAdd(&bcur[t], hist[t]);
    __syncthreads();
    #pragma unroll
    for (int i = 0; i < EPB / 512; i++) {
        int e = base + i * 512 + t;
        if (e < E) {
            int d = col[e], b = d >> NB_SHIFT;
            int p = atomicAdd(&cur[b], 1);
            sorted[bbase[b] + p] = ((unsigned)row[e] << NB_SHIFT) | (unsigned)(d & (NB_W - 1));
        }
    }
}

// One 512-thread block per bucket: count -> scan -> rowptr/dis/csr_src.
__global__ __launch_bounds__(512) void k_build(const unsigned* __restrict__ sorted,
                                               const int* __restrict__ bbase,
                                               int* __restrict__ csr_src,
                                               int* __restrict__ rowptr,
                                               float* __restrict__ dis, int N) {
    __shared__ int cnt[NB_W];
    __shared__ int excl[NB_W];
    __shared__ int wsum[8];
    int b = blockIdx.x, t = threadIdx.x;
    cnt[t] = 0;
    __syncthreads();
    int s0 = bbase[b], s1 = bbase[b + 1];
    for (int p = s0 + t; p < s1; p += 512)
        atomicAdd(&cnt[sorted[p] & (NB_W - 1)], 1);
    __syncthreads();
    int v = cnt[t];
    int lane = t & 63, wid = t >> 6;
    int sc = v;
    #pragma unroll
    for (int off = 1; off < 64; off <<= 1) {
        int u = __shfl_up(sc, off);
        if (lane >= off) sc += u;
    }
    if (lane == 63) wsum[wid] = sc;
    __syncthreads();
    int offs = 0;
    for (int w = 0; w < wid; w++) offs += wsum[w];
    int e0 = offs + sc - v;
    excl[t] = e0;
    int d = (b << NB_SHIFT) + t;
    if (d < N) { rowptr[d] = s0 + e0; dis[d] = rsqrtf((float)(v + 1)); }
    __syncthreads();
    for (int p = s0 + t; p < s1; p += 512) {
        unsigned sd = sorted[p];
        int q = atomicAdd(&excl[sd & (NB_W - 1)], 1);
        csr_src[s0 + q] = (int)(sd >> NB_SHIFT);
    }
}

// ---------------- W prep: Wt[l][n][k] = (fp16) W_l[k][n] ----------------

__global__ __launch_bounds__(256) void k_wprep(const float* __restrict__ W0,
                                               const float* __restrict__ W1,
                                               const float* __restrict__ W2,
                                               _Float16* __restrict__ Wt) {
    int l = blockIdx.x >> 4;
    int chunk = blockIdx.x & 15;
    const float* W = (l == 0) ? W0 : (l == 1) ? W1 : W2;
    _Float16* D = Wt + (size_t)l * HID * HID;
    int t = threadIdx.x;
    int k  = chunk * 8 + (t >> 5);
    int n0 = (t & 31) * 4;
    float4 v = *(const float4*)(W + (size_t)k * HID + n0);
    D[(size_t)(n0 + 0) * HID + k] = (_Float16)v.x;
    D[(size_t)(n0 + 1) * HID + k] = (_Float16)v.y;
    D[(size_t)(n0 + 2) * HID + k] = (_Float16)v.z;
    D[(size_t)(n0 + 3) * HID + k] = (_Float16)v.w;
}

// ---------------- GEMM: T'(8-slice fp16) = dis[row] * (A @ W) via MFMA ----
// B (whole 128x128 Wt) register-resident; wave grid-strides 16-row strips.
// C 8-slice layout: elem (r, c) at [(c>>4)*N + r]*16 + (c&15).

__device__ __forceinline__ half8 load_afrag(const float* A, int arow, int k0, int N) {
    const float* p = A + (size_t)arow * HID + k0;
    float4 v0 = *(const float4*)p;
    float4 v1 = *(const float4*)(p + 4);
    half8 h;
    h[0] = (_Float16)v0.x; h[1] = (_Float16)v0.y;
    h[2] = (_Float16)v0.z; h[3] = (_Float16)v0.w;
    h[4] = (_Float16)v1.x; h[5] = (_Float16)v1.y;
    h[6] = (_Float16)v1.z; h[7] = (_Float16)v1.w;
    return h;
}
__device__ __forceinline__ half8 load_afrag(const _Float16* A, int arow, int k0, int N) {
    return *(const half8*)(A + ((size_t)(k0 >> 4) * N + arow) * 16 + (k0 & 15));
}

template <typename AT>
__global__ __launch_bounds__(256, 2) void k_gemm(const AT* __restrict__ A,
                                                 const _Float16* __restrict__ Wt,
                                                 const float* __restrict__ dis,
                                                 __half* __restrict__ C, int N) {
    const int lane = threadIdx.x & 63;
    const int quad = lane >> 4;
    const int mc   = lane & 15;
    const int gw   = (blockIdx.x * 256 + threadIdx.x) >> 6;
    const int nw   = (gridDim.x * 256) >> 6;
    const int nstrips = (N + 15) >> 4;

    half8 b[8][4];
    #pragma unroll
    for (int j = 0; j < 8; j++)
        #pragma unroll
        for (int s = 0; s < 4; s++)
            b[j][s] = *(const half8*)(Wt + (size_t)(j * 16 + mc) * HID + s * 32 + quad * 8);

    int strip = gw;
    if (strip >= nstrips) return;

    half8 a[4];
    {
        int arow = strip * 16 + mc; if (arow >= N) arow = N - 1;
        #pragma unroll
        for (int s = 0; s < 4; s++) a[s] = load_afrag(A, arow, s * 32 + quad * 8, N);
    }

    for (; strip < nstrips; strip += nw) {
        const int row0 = strip * 16;
        const int next = strip + nw;
        half8 an[4];
        if (next < nstrips) {
            int arow = next * 16 + mc; if (arow >= N) arow = N - 1;
            #pragma unroll
            for (int s = 0; s < 4; s++) an[s] = load_afrag(A, arow, s * 32 + quad * 8, N);
        }
        floatx4 acc[8];
        #pragma unroll
        for (int j = 0; j < 8; j++) acc[j] = (floatx4){0.f, 0.f, 0.f, 0.f};
        #pragma unroll
        for (int s = 0; s < 4; s++)
            #pragma unroll
            for (int j = 0; j < 8; j++)
                acc[j] = __builtin_amdgcn_mfma_f32_16x16x32_f16(a[s], b[j][s], acc[j], 0, 0, 0);
        #pragma unroll
        for (int r = 0; r < 4; r++) {
            int gr = row0 + quad * 4 + r;
            if (gr < N) {
                float ds = dis[gr];
                #pragma unroll
                for (int j = 0; j < 8; j++)
                    C[((size_t)j * N + gr) * 16 + mc] = __float2half(ds * acc[j][r]);
            }
        }
        #pragma unroll
        for (int s = 0; s < 4; s++) a[s] = an[s];
    }
}

// ---------------- aggregation (8 feature-slice passes, XCD-resident) ------
// pass = blockIdx & 7 == XCD id under round-robin block->XCD dispatch, so
// XCD p gathers ONLY slice p: 100k * 32 B = 3.2 MB, resident in its 4 MB
// L2 for the whole dispatch. csr_src loads and out stores are non-temporal
// so the streams don't evict the slice. 8 lanes per dst: p = edge slot (4),
// h = float4 slot (2); 32 dsts per 256-thread block.

__device__ __forceinline__ void add8(float* acc, float4 r) {
    __half2* h = (__half2*)&r;
    #pragma unroll
    for (int k = 0; k < 4; k++) {
        float2 v = __half22float2(h[k]);
        acc[2 * k]     += v.x;
        acc[2 * k + 1] += v.y;
    }
}

__global__ __launch_bounds__(256) void k_agg(const __half* __restrict__ T,
                                             const float* __restrict__ dis,
                                             const int* __restrict__ rowptr,
                                             const int* __restrict__ csr_src,
                                             const float* __restrict__ bias,
                                             __half* __restrict__ out, int N) {
    const int b    = blockIdx.x;
    const int pass = b & 7;            // == XCD id (round-robin dispatch)
    const int nbi  = b >> 3;
    const int t    = threadIdx.x;
    const int l    = t & 7;
    const int p    = l >> 1;           // 4 edge slots
    const int h    = l & 1;            // 2 float4 per 32 B node-slice
    const int n = nbi * 32 + (t >> 3);
    if (n >= N) return;

    const float4* T4 = (const float4*)(T + (size_t)pass * N * 16);

    float acc[8] = {};

    int e  = rowptr[n];
    int e1 = rowptr[n + 1];
    for (; e + 16 <= e1; e += 16) {
        int s0 = __builtin_nontemporal_load(csr_src + e + p);
        int s1 = __builtin_nontemporal_load(csr_src + e + 4 + p);
        int s2 = __builtin_nontemporal_load(csr_src + e + 8 + p);
        int s3 = __builtin_nontemporal_load(csr_src + e + 12 + p);
        float4 r0 = T4[(size_t)s0 * 2 + h];
        float4 r1 = T4[(size_t)s1 * 2 + h];
        float4 r2 = T4[(size_t)s2 * 2 + h];
        float4 r3 = T4[(size_t)s3 * 2 + h];
        add8(acc, r0); add8(acc, r1); add8(acc, r2); add8(acc, r3);
    }
    for (; e + 4 <= e1; e += 4) {
        int s = __builtin_nontemporal_load(csr_src + e + p);
        add8(acc, T4[(size_t)s * 2 + h]);
    }
    if (e + p < e1) {
        int s = __builtin_nontemporal_load(csr_src + e + p);
        add8(acc, T4[(size_t)s * 2 + h]);
    }
    if (p == 0) add8(acc, T4[(size_t)n * 2 + h]);   // self-loop

    #pragma unroll
    for (int k = 0; k < 8; k++) {
        acc[k] += __shfl_xor(acc[k], 2, 64);
        acc[k] += __shfl_xor(acc[k], 4, 64);
    }

    if (p == 0) {
        float dn = dis[n];
        half8 o;
        #pragma unroll
        for (int k = 0; k < 8; k++) {
            float v = fmaf(dn, acc[k], bias[pass * 16 + h * 8 + k]);
            o[k] = (_Float16)fmaxf(v, 0.f);
        }
        __builtin_nontemporal_store(
            o, (half8*)((_Float16*)out + ((size_t)pass * N + n) * 16 + h * 8));
    }
}

// ---------------- fused mean-pool + MLP head ----------------

__device__ __forceinline__ int lbound(const int* __restrict__ batch, int N, int g) {
    int lo = 0, hi = N;
    while (lo < hi) {
        int mid = (lo + hi) >> 1;
        if (batch[mid] < g) lo = mid + 1; else hi = mid;
    }
    return lo;
}

__global__ __launch_bounds__(256) void k_poolmlp(const __half* __restrict__ hbuf,
                                                 const int* __restrict__ batch,
                                                 const float* __restrict__ Wm0,
                                                 const float* __restrict__ bm0,
                                                 const float* __restrict__ Wm1,
                                                 const float* __restrict__ bm1,
                                                 float* __restrict__ out, int N) {
    __shared__ float red[2048];
    __shared__ float g[HID];
    const int gr = blockIdx.x, t = threadIdx.x;
    const int s = lbound(batch, N, gr), e = lbound(batch, N, gr + 1);

    const int rg = t >> 4, cl = t & 15;
    // 8-slice layout: chunk cl covers features [cl*8, cl*8+8) ->
    // slice cl>>1, in-slice offset (cl&1)*8, row stride 16.
    const _Float16* base = (const _Float16*)hbuf
        + (size_t)(cl >> 1) * N * 16 + (size_t)(cl & 1) * 8;
    float acc[8] = {};
    for (int r = s + rg; r < e; r += 16) {
        half8 v = *(const half8*)(base + (size_t)r * 16);
        #pragma unroll
        for (int k = 0; k < 8; k++) acc[k] += (float)v[k];
    }
    #pragma unroll
    for (int k = 0; k < 8; k++) red[t * 8 + k] = acc[k];
    __syncthreads();
    if (t < 128) {
        int cl2 = t >> 3, k = t & 7;
        float sm = 0.f;
        #pragma unroll
        for (int rg2 = 0; rg2 < 16; rg2++) sm += red[(rg2 * 16 + cl2) * 8 + k];
        int feat = (cl2 >> 1) * 16 + (cl2 & 1) * 8 + k;
        g[feat] = sm / fmaxf((float)(e - s), 1.f);
    }
    __syncthreads();

    const int j = t & 127, hh = t >> 7;
    float a = 0.f;
    for (int k = hh * 64; k < hh * 64 + 64; k++)
        a = fmaf(g[k], Wm0[(size_t)k * HID + j], a);
    red[hh * 128 + j] = a;
    __syncthreads();

    if (t < 128) {
        float h1 = fmaxf(bm0[j] + red[j] + red[128 + j], 0.f);
        float z = h1 * Wm1[j];
        #pragma unroll
        for (int off = 32; off > 0; off >>= 1) z += __shfl_xor(z, off, 64);
        if ((t & 63) == 0) red[1024 + (t >> 6)] = z;
    }
    __syncthreads();
    if (t == 0) out[gr] = red[1024] + red[1025] + bm1[0];
}

// ---------------- launch ----------------

extern "C" void kernel_launch(void* const* d_in, const int* in_sizes, int n_in,
                              void* d_out, int out_size, void* d_ws, size_t ws_size,
                              hipStream_t stream) {
    const float* x     = (const float*)d_in[0];
    const int*   ei    = (const int*)d_in[1];
    const int*   batch = (const int*)d_in[3];
    const float* W0 = (const float*)d_in[4],  *b0 = (const float*)d_in[5];
    const float* W1 = (const float*)d_in[6],  *b1 = (const float*)d_in[7];
    const float* W2 = (const float*)d_in[8],  *b2 = (const float*)d_in[9];
    const float* Wm0 = (const float*)d_in[10], *bm0 = (const float*)d_in[11];
    const float* Wm1 = (const float*)d_in[12], *bm1 = (const float*)d_in[13];

    const int N = in_sizes[0] / HID;
    const int E = in_sizes[1] / 2;
    const int nb = (N + NB_W - 1) >> NB_SHIFT;
    const int* row  = ei;
    const int* colI = ei + E;

    char* w = (char*)d_ws;
    auto carve = [&](size_t bytes) {
        void* p = (void*)w;
        w += (bytes + 255) & ~(size_t)255;
        return p;
    };
    int*      ibuf    = (int*)     carve(512 * 4);
    int*      bbase   = (int*)     carve(257 * 4);
    float*    dis     = (float*)   carve((size_t)N * 4);
    int*      rowptr  = (int*)     carve((size_t)(N + 1) * 4);
    unsigned* sorted  = (unsigned*)carve((size_t)E * 4);
    int*      csr_src = (int*)     carve((size_t)E * 4);
    _Float16* wth     = (_Float16*)carve((size_t)3 * HID * HID * 2);
    __half*   bufT    = (__half*)  carve((size_t)N * HID * 2);
    __half*   bufA    = (__half*)  carve((size_t)N * HID * 2);
    __half*   bufB    = (__half*)  carve((size_t)N * HID * 2);

    int* ghist = ibuf;
    int* bcur  = ibuf + 256;

    hipMemsetAsync(ibuf, 0, 512 * 4, stream);
    k_wprep  <<<48, 256, 0, stream>>>(W0, W1, W2, wth);
    k_hist   <<<512, 256, 0, stream>>>(colI, ghist, E, nb);
    k_bscan  <<<1, 256, 0, stream>>>(ghist, bbase, rowptr, N, E, nb);
    k_scatter<<<(E + EPB - 1) / EPB, 512, 0, stream>>>(row, colI, bbase, bcur, sorted, E);
    k_build  <<<nb, 512, 0, stream>>>(sorted, bbase, csr_src, rowptr, dis, N);

    dim3 gg(512);
    const int npb = (N + 31) / 32;          // dst-blocks per pass (32 dst/block)
    dim3 ga(8 * npb);                       // 8 slice passes, pass = blockIdx & 7

    k_gemm<float>    <<<gg, 256, 0, stream>>>(x, wth, dis, bufT, N);
    k_agg            <<<ga, 256, 0, stream>>>(bufT, dis, rowptr, csr_src, b0, bufA, N);
    k_gemm<_Float16> <<<gg, 256, 0, stream>>>((const _Float16*)bufA, wth + HID * HID, dis, bufT, N);
    k_agg            <<<ga, 256, 0, stream>>>(bufT, dis, rowptr, csr_src, b1, bufB, N);
    k_gemm<_Float16> <<<gg, 256, 0, stream>>>((const _Float16*)bufB, wth + 2 * HID * HID, dis, bufT, N);
    k_agg            <<<ga, 256, 0, stream>>>(bufT, dis, rowptr, csr_src, b2, bufA, N);

    k_poolmlp<<<NGR, 256, 0, stream>>>(bufA, batch, Wm0, bm0, Wm1, bm1, (float*)d_out, N);
}

// Round 2
// 831.036 us; speedup vs baseline: 1.2099x; 1.2099x over previous
//
#include <hip/hip_runtime.h>
#include <hip/hip_fp16.h>

// GCNRegressor: 3x GCNConv(128->128) + mean-pool + 2-layer MLP head.
// CSR-by-dst bucket sort; MFMA fp16 GEMM with register-resident B; T in
// EIGHT 16-feature slices (3.2 MB/slice -> fits a 4 MB per-XCD L2); agg
// runs 8 passes with pass = blockIdx%8 so (round-robin block->XCD
// dispatch) XCD p exclusively gathers slice p from its own L2 (verified:
// FETCH 312->135 MB). csr indices are staged into LDS via coalesced nt
// loads (latency-hidden; nt keeps the slice resident), so the per-edge
// chain is LDS-read -> L2-hit gather. 4 lanes/dst, 32B gather per edge.
// fused mean-pool + MLP head. f32 accumulate everywhere.

#define HID 128
#define NGR 512
#define NB_SHIFT 9
#define NB_W 512
#define EPB 4096
#define AGG_CHUNK 4096

typedef __attribute__((ext_vector_type(8))) _Float16 half8;
typedef __attribute__((ext_vector_type(4))) float floatx4;

// ---------------- graph prep: bucket sort by destination ----------------

__global__ __launch_bounds__(256) void k_hist(const int* __restrict__ col,
                                              int* __restrict__ ghist, int E, int nb) {
    __shared__ int h[256];
    h[threadIdx.x] = 0;
    __syncthreads();
    for (int e = blockIdx.x * 256 + threadIdx.x; e < E; e += gridDim.x * 256)
        atomicAdd(&h[col[e] >> NB_SHIFT], 1);
    __syncthreads();
    int t = threadIdx.x;
    if (t < nb && h[t]) atomicAdd(&ghist[t], h[t]);
}

__global__ __launch_bounds__(256) void k_bscan(const int* __restrict__ ghist,
                                               int* __restrict__ bbase,
                                               int* __restrict__ rowptr,
                                               int N, int E, int nb) {
    __shared__ int wsum[4];
    int t = threadIdx.x, lane = t & 63, wid = t >> 6;
    int v = (t < nb) ? ghist[t] : 0;
    int sc = v;
    #pragma unroll
    for (int off = 1; off < 64; off <<= 1) {
        int u = __shfl_up(sc, off);
        if (lane >= off) sc += u;
    }
    if (lane == 63) wsum[wid] = sc;
    __syncthreads();
    int offs = 0;
    for (int w = 0; w < wid; w++) offs += wsum[w];
    int excl = offs + sc - v;
    if (t <= nb) bbase[t] = excl;
    if (t == 0) rowptr[N] = E;
}

// packed entry: (src << 9) | (dst & 511)
__global__ __launch_bounds__(512) void k_scatter(const int* __restrict__ row,
                                                 const int* __restrict__ col,
                                                 const int* __restrict__ bbase,
                                                 int* __restrict__ bcur,
                                                 unsigned* __restrict__ sorted, int E) {
    __shared__ int hist[256];
    __shared__ int cur[256];
    int t = threadIdx.x;
    if (t < 256) hist[t] = 0;
    __syncthreads();
    int base = blockIdx.x * EPB;
    #pragma unroll
    for (int i = 0; i < EPB / 512; i++) {
        int e = base + i * 512 + t;
        if (e < E) atomicAdd(&hist[col[e] >> NB_SHIFT], 1);
    }
    __syncthreads();
    if (t < 256 && hist[t] > 0) cur[t] = atomicAdd(&bcur[t], hist[t]);
    __syncthreads();
    #pragma unroll
    for (int i = 0; i < EPB / 512; i++) {
        int e = base + i * 512 + t;
        if (e < E) {
            int d = col[e], b = d >> NB_SHIFT;
            int p = atomicAdd(&cur[b], 1);
            sorted[bbase[b] + p] = ((unsigned)row[e] << NB_SHIFT) | (unsigned)(d & (NB_W - 1));
        }
    }
}

// One 512-thread block per bucket: count -> scan -> rowptr/dis/csr_src.
__global__ __launch_bounds__(512) void k_build(const unsigned* __restrict__ sorted,
                                               const int* __restrict__ bbase,
                                               int* __restrict__ csr_src,
                                               int* __restrict__ rowptr,
                                               float* __restrict__ dis, int N) {
    __shared__ int cnt[NB_W];
    __shared__ int excl[NB_W];
    __shared__ int wsum[8];
    int b = blockIdx.x, t = threadIdx.x;
    cnt[t] = 0;
    __syncthreads();
    int s0 = bbase[b], s1 = bbase[b + 1];
    for (int p = s0 + t; p < s1; p += 512)
        atomicAdd(&cnt[sorted[p] & (NB_W - 1)], 1);
    __syncthreads();
    int v = cnt[t];
    int lane = t & 63, wid = t >> 6;
    int sc = v;
    #pragma unroll
    for (int off = 1; off < 64; off <<= 1) {
        int u = __shfl_up(sc, off);
        if (lane >= off) sc += u;
    }
    if (lane == 63) wsum[wid] = sc;
    __syncthreads();
    int offs = 0;
    for (int w = 0; w < wid; w++) offs += wsum[w];
    int e0 = offs + sc - v;
    excl[t] = e0;
    int d = (b << NB_SHIFT) + t;
    if (d < N) { rowptr[d] = s0 + e0; dis[d] = rsqrtf((float)(v + 1)); }
    __syncthreads();
    for (int p = s0 + t; p < s1; p += 512) {
        unsigned sd = sorted[p];
        int q = atomicAdd(&excl[sd & (NB_W - 1)], 1);
        csr_src[s0 + q] = (int)(sd >> NB_SHIFT);
    }
}

// ---------------- W prep: Wt[l][n][k] = (fp16) W_l[k][n] ----------------

__global__ __launch_bounds__(256) void k_wprep(const float* __restrict__ W0,
                                               const float* __restrict__ W1,
                                               const float* __restrict__ W2,
                                               _Float16* __restrict__ Wt) {
    int l = blockIdx.x >> 4;
    int chunk = blockIdx.x & 15;
    const float* W = (l == 0) ? W0 : (l == 1) ? W1 : W2;
    _Float16* D = Wt + (size_t)l * HID * HID;
    int t = threadIdx.x;
    int k  = chunk * 8 + (t >> 5);
    int n0 = (t & 31) * 4;
    float4 v = *(const float4*)(W + (size_t)k * HID + n0);
    D[(size_t)(n0 + 0) * HID + k] = (_Float16)v.x;
    D[(size_t)(n0 + 1) * HID + k] = (_Float16)v.y;
    D[(size_t)(n0 + 2) * HID + k] = (_Float16)v.z;
    D[(size_t)(n0 + 3) * HID + k] = (_Float16)v.w;
}

// ---------------- GEMM: T'(8-slice fp16) = dis[row] * (A @ W) via MFMA ----
// B (whole 128x128 Wt) register-resident; wave grid-strides 16-row strips.
// C 8-slice layout: elem (r, c) at [(c>>4)*N + r]*16 + (c&15).

__device__ __forceinline__ half8 load_afrag(const float* A, int arow, int k0, int N) {
    const float* p = A + (size_t)arow * HID + k0;
    float4 v0 = *(const float4*)p;
    float4 v1 = *(const float4*)(p + 4);
    half8 h;
    h[0] = (_Float16)v0.x; h[1] = (_Float16)v0.y;
    h[2] = (_Float16)v0.z; h[3] = (_Float16)v0.w;
    h[4] = (_Float16)v1.x; h[5] = (_Float16)v1.y;
    h[6] = (_Float16)v1.z; h[7] = (_Float16)v1.w;
    return h;
}
__device__ __forceinline__ half8 load_afrag(const _Float16* A, int arow, int k0, int N) {
    return *(const half8*)(A + ((size_t)(k0 >> 4) * N + arow) * 16 + (k0 & 15));
}

template <typename AT>
__global__ __launch_bounds__(256, 2) void k_gemm(const AT* __restrict__ A,
                                                 const _Float16* __restrict__ Wt,
                                                 const float* __restrict__ dis,
                                                 __half* __restrict__ C, int N) {
    const int lane = threadIdx.x & 63;
    const int quad = lane >> 4;
    const int mc   = lane & 15;
    const int gw   = (blockIdx.x * 256 + threadIdx.x) >> 6;
    const int nw   = (gridDim.x * 256) >> 6;
    const int nstrips = (N + 15) >> 4;

    half8 b[8][4];
    #pragma unroll
    for (int j = 0; j < 8; j++)
        #pragma unroll
        for (int s = 0; s < 4; s++)
            b[j][s] = *(const half8*)(Wt + (size_t)(j * 16 + mc) * HID + s * 32 + quad * 8);

    int strip = gw;
    if (strip >= nstrips) return;

    half8 a[4];
    {
        int arow = strip * 16 + mc; if (arow >= N) arow = N - 1;
        #pragma unroll
        for (int s = 0; s < 4; s++) a[s] = load_afrag(A, arow, s * 32 + quad * 8, N);
    }

    for (; strip < nstrips; strip += nw) {
        const int row0 = strip * 16;
        const int next = strip + nw;
        half8 an[4];
        if (next < nstrips) {
            int arow = next * 16 + mc; if (arow >= N) arow = N - 1;
            #pragma unroll
            for (int s = 0; s < 4; s++) an[s] = load_afrag(A, arow, s * 32 + quad * 8, N);
        }
        floatx4 acc[8];
        #pragma unroll
        for (int j = 0; j < 8; j++) acc[j] = (floatx4){0.f, 0.f, 0.f, 0.f};
        #pragma unroll
        for (int s = 0; s < 4; s++)
            #pragma unroll
            for (int j = 0; j < 8; j++)
                acc[j] = __builtin_amdgcn_mfma_f32_16x16x32_f16(a[s], b[j][s], acc[j], 0, 0, 0);
        #pragma unroll
        for (int r = 0; r < 4; r++) {
            int gr = row0 + quad * 4 + r;
            if (gr < N) {
                float ds = dis[gr];
                #pragma unroll
                for (int j = 0; j < 8; j++)
                    C[((size_t)j * N + gr) * 16 + mc] = __float2half(ds * acc[j][r]);
            }
        }
        #pragma unroll
        for (int s = 0; s < 4; s++) a[s] = an[s];
    }
}

// ---------------- aggregation (8 slice passes, XCD-resident, LDS idx) -----
// pass = blockIdx & 7 == XCD id under round-robin dispatch. Block owns 64
// contiguous dsts -> their csr range is contiguous: stage it into LDS with
// coalesced nt loads (latency hidden, slice stays L2-resident). 4 lanes per
// dst (p = edge slot); each lane gathers the full 32B node-slice per edge.

__device__ __forceinline__ void add8(float* acc, float4 r) {
    __half2* h = (__half2*)&r;
    #pragma unroll
    for (int k = 0; k < 4; k++) {
        float2 v = __half22float2(h[k]);
        acc[2 * k]     += v.x;
        acc[2 * k + 1] += v.y;
    }
}

__global__ __launch_bounds__(256) void k_agg(const __half* __restrict__ T,
                                             const float* __restrict__ dis,
                                             const int* __restrict__ rowptr,
                                             const int* __restrict__ csr_src,
                                             const float* __restrict__ bias,
                                             __half* __restrict__ out, int N) {
    __shared__ int sidx[AGG_CHUNK];
    const int b    = blockIdx.x;
    const int pass = b & 7;            // == XCD id (round-robin dispatch)
    const int nbi  = b >> 3;
    const int t    = threadIdx.x;
    const int p    = t & 3;            // 4 edge slots per dst
    const int n0   = nbi * 64;
    const int n    = n0 + (t >> 2);
    const bool act = (n < N);

    const int blk_e0 = rowptr[n0];
    const int blk_e1 = rowptr[(n0 + 64 < N) ? (n0 + 64) : N];

    const float4* T4 = (const float4*)(T + (size_t)pass * N * 16);

    float acc[16] = {};
    int mye = 0;
    int e   = 0;
    if (act) { e = rowptr[n] + p; mye = rowptr[n + 1]; }

    for (int cb = blk_e0; cb < blk_e1; cb += AGG_CHUNK) {
        const int cend = (cb + AGG_CHUNK < blk_e1) ? (cb + AGG_CHUNK) : blk_e1;
        __syncthreads();
        for (int i = cb + t; i < cend; i += 256)
            sidx[i - cb] = __builtin_nontemporal_load(csr_src + i);
        __syncthreads();
        const int bnd = (mye < cend) ? mye : cend;
        // 2-edge unroll (4 x 16B gathers in flight per lane)
        for (; e + 4 < bnd; e += 8) {
            int i0 = sidx[e - cb];
            int i1 = sidx[e + 4 - cb];
            float4 r0 = T4[(size_t)i0 * 2];
            float4 r1 = T4[(size_t)i0 * 2 + 1];
            float4 r2 = T4[(size_t)i1 * 2];
            float4 r3 = T4[(size_t)i1 * 2 + 1];
            add8(acc, r0); add8(acc + 8, r1);
            add8(acc, r2); add8(acc + 8, r3);
        }
        for (; e < bnd; e += 4) {
            int i0 = sidx[e - cb];
            float4 r0 = T4[(size_t)i0 * 2];
            float4 r1 = T4[(size_t)i0 * 2 + 1];
            add8(acc, r0); add8(acc + 8, r1);
        }
    }

    if (act && p == 0) {               // self-loop
        add8(acc,     T4[(size_t)n * 2]);
        add8(acc + 8, T4[(size_t)n * 2 + 1]);
    }

    #pragma unroll
    for (int k = 0; k < 16; k++) {
        acc[k] += __shfl_xor(acc[k], 1, 64);
        acc[k] += __shfl_xor(acc[k], 2, 64);
    }

    if (act && p == 0) {
        float dn = dis[n];
        half8 o0, o1;
        #pragma unroll
        for (int k = 0; k < 8; k++) {
            float v0 = fmaf(dn, acc[k],     bias[pass * 16 + k]);
            float v1 = fmaf(dn, acc[8 + k], bias[pass * 16 + 8 + k]);
            o0[k] = (_Float16)fmaxf(v0, 0.f);
            o1[k] = (_Float16)fmaxf(v1, 0.f);
        }
        _Float16* dst = (_Float16*)out + ((size_t)pass * N + n) * 16;
        __builtin_nontemporal_store(o0, (half8*)dst);
        __builtin_nontemporal_store(o1, (half8*)(dst + 8));
    }
}

// ---------------- fused mean-pool + MLP head ----------------

__device__ __forceinline__ int lbound(const int* __restrict__ batch, int N, int g) {
    int lo = 0, hi = N;
    while (lo < hi) {
        int mid = (lo + hi) >> 1;
        if (batch[mid] < g) lo = mid + 1; else hi = mid;
    }
    return lo;
}

__global__ __launch_bounds__(256) void k_poolmlp(const __half* __restrict__ hbuf,
                                                 const int* __restrict__ batch,
                                                 const float* __restrict__ Wm0,
                                                 const float* __restrict__ bm0,
                                                 const float* __restrict__ Wm1,
                                                 const float* __restrict__ bm1,
                                                 float* __restrict__ out, int N) {
    __shared__ float red[2048];
    __shared__ float g[HID];
    const int gr = blockIdx.x, t = threadIdx.x;
    const int s = lbound(batch, N, gr), e = lbound(batch, N, gr + 1);

    const int rg = t >> 4, cl = t & 15;
    // 8-slice layout: chunk cl covers features [cl*8, cl*8+8) ->
    // slice cl>>1, in-slice offset (cl&1)*8, row stride 16.
    const _Float16* base = (const _Float16*)hbuf
        + (size_t)(cl >> 1) * N * 16 + (size_t)(cl & 1) * 8;
    float acc[8] = {};
    for (int r = s + rg; r < e; r += 16) {
        half8 v = *(const half8*)(base + (size_t)r * 16);
        #pragma unroll
        for (int k = 0; k < 8; k++) acc[k] += (float)v[k];
    }
    #pragma unroll
    for (int k = 0; k < 8; k++) red[t * 8 + k] = acc[k];
    __syncthreads();
    if (t < 128) {
        int cl2 = t >> 3, k = t & 7;
        float sm = 0.f;
        #pragma unroll
        for (int rg2 = 0; rg2 < 16; rg2++) sm += red[(rg2 * 16 + cl2) * 8 + k];
        int feat = (cl2 >> 1) * 16 + (cl2 & 1) * 8 + k;
        g[feat] = sm / fmaxf((float)(e - s), 1.f);
    }
    __syncthreads();

    const int j = t & 127, hh = t >> 7;
    float a = 0.f;
    for (int k = hh * 64; k < hh * 64 + 64; k++)
        a = fmaf(g[k], Wm0[(size_t)k * HID + j], a);
    red[hh * 128 + j] = a;
    __syncthreads();

    if (t < 128) {
        float h1 = fmaxf(bm0[j] + red[j] + red[128 + j], 0.f);
        float z = h1 * Wm1[j];
        #pragma unroll
        for (int off = 32; off > 0; off >>= 1) z += __shfl_xor(z, off, 64);
        if ((t & 63) == 0) red[1024 + (t >> 6)] = z;
    }
    __syncthreads();
    if (t == 0) out[gr] = red[1024] + red[1025] + bm1[0];
}

// ---------------- launch ----------------

extern "C" void kernel_launch(void* const* d_in, const int* in_sizes, int n_in,
                              void* d_out, int out_size, void* d_ws, size_t ws_size,
                              hipStream_t stream) {
    const float* x     = (const float*)d_in[0];
    const int*   ei    = (const int*)d_in[1];
    const int*   batch = (const int*)d_in[3];
    const float* W0 = (const float*)d_in[4],  *b0 = (const float*)d_in[5];
    const float* W1 = (const float*)d_in[6],  *b1 = (const float*)d_in[7];
    const float* W2 = (const float*)d_in[8],  *b2 = (const float*)d_in[9];
    const float* Wm0 = (const float*)d_in[10], *bm0 = (const float*)d_in[11];
    const float* Wm1 = (const float*)d_in[12], *bm1 = (const float*)d_in[13];

    const int N = in_sizes[0] / HID;
    const int E = in_sizes[1] / 2;
    const int nb = (N + NB_W - 1) >> NB_SHIFT;
    const int* row  = ei;
    const int* colI = ei + E;

    char* w = (char*)d_ws;
    auto carve = [&](size_t bytes) {
        void* p = (void*)w;
        w += (bytes + 255) & ~(size_t)255;
        return p;
    };
    int*      ibuf    = (int*)     carve(512 * 4);
    int*      bbase   = (int*)     carve(257 * 4);
    float*    dis     = (float*)   carve((size_t)N * 4);
    int*      rowptr  = (int*)     carve((size_t)(N + 1) * 4);
    unsigned* sorted  = (unsigned*)carve((size_t)E * 4);
    int*      csr_src = (int*)     carve((size_t)E * 4);
    _Float16* wth     = (_Float16*)carve((size_t)3 * HID * HID * 2);
    __half*   bufT    = (__half*)  carve((size_t)N * HID * 2);
    __half*   bufA    = (__half*)  carve((size_t)N * HID * 2);
    __half*   bufB    = (__half*)  carve((size_t)N * HID * 2);

    int* ghist = ibuf;
    int* bcur  = ibuf + 256;

    hipMemsetAsync(ibuf, 0, 512 * 4, stream);
    k_wprep  <<<48, 256, 0, stream>>>(W0, W1, W2, wth);
    k_hist   <<<512, 256, 0, stream>>>(colI, ghist, E, nb);
    k_bscan  <<<1, 256, 0, stream>>>(ghist, bbase, rowptr, N, E, nb);
    k_scatter<<<(E + EPB - 1) / EPB, 512, 0, stream>>>(row, colI, bbase, bcur, sorted, E);
    k_build  <<<nb, 512, 0, stream>>>(sorted, bbase, csr_src, rowptr, dis, N);

    dim3 gg(512);
    const int npb = (N + 63) / 64;          // dst-blocks per pass (64 dst/block)
    dim3 ga(8 * npb);                       // 8 slice passes, pass = blockIdx & 7

    k_gemm<float>    <<<gg, 256, 0, stream>>>(x, wth, dis, bufT, N);
    k_agg            <<<ga, 256, 0, stream>>>(bufT, dis, rowptr, csr_src, b0, bufA, N);
    k_gemm<_Float16> <<<gg, 256, 0, stream>>>((const _Float16*)bufA, wth + HID * HID, dis, bufT, N);
    k_agg            <<<ga, 256, 0, stream>>>(bufT, dis, rowptr, csr_src, b1, bufB, N);
    k_gemm<_Float16> <<<gg, 256, 0, stream>>>((const _Float16*)bufB, wth + 2 * HID * HID, dis, bufT, N);
    k_agg            <<<ga, 256, 0, stream>>>(bufT, dis, rowptr, csr_src, b2, bufA, N);

    k_poolmlp<<<NGR, 256, 0, stream>>>(bufA, batch, Wm0, bm0, Wm1, bm1, (float*)d_out, N);
}

// Round 3
// 821.710 us; speedup vs baseline: 1.2236x; 1.0114x over previous
//
#include <hip/hip_runtime.h>
#include <hip/hip_fp16.h>

// GCNRegressor: 3x GCNConv(128->128) + mean-pool + 2-layer MLP head.
// CSR-by-dst bucket sort; MFMA fp16 GEMM with register-resident B; T in
// EIGHT 16-feature slices (3.2 MB/slice -> fits a 4 MB per-XCD L2); agg
// runs 8 passes with pass = blockIdx%8 so (round-robin block->XCD
// dispatch) XCD p exclusively gathers slice p from its own L2 (verified:
// FETCH 312->70 MB). csr indices staged into LDS via coalesced nt loads.
// Gathers are 2-lane coalesced: lanes h=0,1 read the two float4 halves of
// the SAME edge's 32 B slice -> ONE L2 line request per edge (k_agg is
// L2-request-rate-bound at ~16 req/cy/XCD; this halves requests vs r2).
// 8 lanes/dst = 4 edge-slots x 2 half-slots; each lane owns 8 features ->
// reduction is 2 shuffles over edge-slots only. f32 accumulate.

#define HID 128
#define NGR 512
#define NB_SHIFT 9
#define NB_W 512
#define EPB 4096
#define AGG_CHUNK 4096

typedef __attribute__((ext_vector_type(8))) _Float16 half8;
typedef __attribute__((ext_vector_type(4))) float floatx4;

// ---------------- graph prep: bucket sort by destination ----------------

__global__ __launch_bounds__(256) void k_hist(const int* __restrict__ col,
                                              int* __restrict__ ghist, int E, int nb) {
    __shared__ int h[256];
    h[threadIdx.x] = 0;
    __syncthreads();
    for (int e = blockIdx.x * 256 + threadIdx.x; e < E; e += gridDim.x * 256)
        atomicAdd(&h[col[e] >> NB_SHIFT], 1);
    __syncthreads();
    int t = threadIdx.x;
    if (t < nb && h[t]) atomicAdd(&ghist[t], h[t]);
}

__global__ __launch_bounds__(256) void k_bscan(const int* __restrict__ ghist,
                                               int* __restrict__ bbase,
                                               int* __restrict__ rowptr,
                                               int N, int E, int nb) {
    __shared__ int wsum[4];
    int t = threadIdx.x, lane = t & 63, wid = t >> 6;
    int v = (t < nb) ? ghist[t] : 0;
    int sc = v;
    #pragma unroll
    for (int off = 1; off < 64; off <<= 1) {
        int u = __shfl_up(sc, off);
        if (lane >= off) sc += u;
    }
    if (lane == 63) wsum[wid] = sc;
    __syncthreads();
    int offs = 0;
    for (int w = 0; w < wid; w++) offs += wsum[w];
    int excl = offs + sc - v;
    if (t <= nb) bbase[t] = excl;
    if (t == 0) rowptr[N] = E;
}

// packed entry: (src << 9) | (dst & 511)
__global__ __launch_bounds__(512) void k_scatter(const int* __restrict__ row,
                                                 const int* __restrict__ col,
                                                 const int* __restrict__ bbase,
                                                 int* __restrict__ bcur,
                                                 unsigned* __restrict__ sorted, int E) {
    __shared__ int hist[256];
    __shared__ int cur[256];
    int t = threadIdx.x;
    if (t < 256) hist[t] = 0;
    __syncthreads();
    int base = blockIdx.x * EPB;
    #pragma unroll
    for (int i = 0; i < EPB / 512; i++) {
        int e = base + i * 512 + t;
        if (e < E) atomicAdd(&hist[col[e] >> NB_SHIFT], 1);
    }
    __syncthreads();
    if (t < 256 && hist[t] > 0) cur[t] = atomicAdd(&bcur[t], hist[t]);
    __syncthreads();
    #pragma unroll
    for (int i = 0; i < EPB / 512; i++) {
        int e = base + i * 512 + t;
        if (e < E) {
            int d = col[e], b = d >> NB_SHIFT;
            int p = atomicAdd(&cur[b], 1);
            sorted[bbase[b] + p] = ((unsigned)row[e] << NB_SHIFT) | (unsigned)(d & (NB_W - 1));
        }
    }
}

// One 512-thread block per bucket: count -> scan -> rowptr/dis/csr_src.
__global__ __launch_bounds__(512) void k_build(const unsigned* __restrict__ sorted,
                                               const int* __restrict__ bbase,
                                               int* __restrict__ csr_src,
                                               int* __restrict__ rowptr,
                                               float* __restrict__ dis, int N) {
    __shared__ int cnt[NB_W];
    __shared__ int excl[NB_W];
    __shared__ int wsum[8];
    int b = blockIdx.x, t = threadIdx.x;
    cnt[t] = 0;
    __syncthreads();
    int s0 = bbase[b], s1 = bbase[b + 1];
    for (int p = s0 + t; p < s1; p += 512)
        atomicAdd(&cnt[sorted[p] & (NB_W - 1)], 1);
    __syncthreads();
    int v = cnt[t];
    int lane = t & 63, wid = t >> 6;
    int sc = v;
    #pragma unroll
    for (int off = 1; off < 64; off <<= 1) {
        int u = __shfl_up(sc, off);
        if (lane >= off) sc += u;
    }
    if (lane == 63) wsum[wid] = sc;
    __syncthreads();
    int offs = 0;
    for (int w = 0; w < wid; w++) offs += wsum[w];
    int e0 = offs + sc - v;
    excl[t] = e0;
    int d = (b << NB_SHIFT) + t;
    if (d < N) { rowptr[d] = s0 + e0; dis[d] = rsqrtf((float)(v + 1)); }
    __syncthreads();
    for (int p = s0 + t; p < s1; p += 512) {
        unsigned sd = sorted[p];
        int q = atomicAdd(&excl[sd & (NB_W - 1)], 1);
        csr_src[s0 + q] = (int)(sd >> NB_SHIFT);
    }
}

// ---------------- W prep: Wt[l][n][k] = (fp16) W_l[k][n] ----------------

__global__ __launch_bounds__(256) void k_wprep(const float* __restrict__ W0,
                                               const float* __restrict__ W1,
                                               const float* __restrict__ W2,
                                               _Float16* __restrict__ Wt) {
    int l = blockIdx.x >> 4;
    int chunk = blockIdx.x & 15;
    const float* W = (l == 0) ? W0 : (l == 1) ? W1 : W2;
    _Float16* D = Wt + (size_t)l * HID * HID;
    int t = threadIdx.x;
    int k  = chunk * 8 + (t >> 5);
    int n0 = (t & 31) * 4;
    float4 v = *(const float4*)(W + (size_t)k * HID + n0);
    D[(size_t)(n0 + 0) * HID + k] = (_Float16)v.x;
    D[(size_t)(n0 + 1) * HID + k] = (_Float16)v.y;
    D[(size_t)(n0 + 2) * HID + k] = (_Float16)v.z;
    D[(size_t)(n0 + 3) * HID + k] = (_Float16)v.w;
}

// ---------------- GEMM: T'(8-slice fp16) = dis[row] * (A @ W) via MFMA ----
// B (whole 128x128 Wt) register-resident; wave grid-strides 16-row strips.
// C 8-slice layout: elem (r, c) at [(c>>4)*N + r]*16 + (c&15).

__device__ __forceinline__ half8 load_afrag(const float* A, int arow, int k0, int N) {
    const float* p = A + (size_t)arow * HID + k0;
    float4 v0 = *(const float4*)p;
    float4 v1 = *(const float4*)(p + 4);
    half8 h;
    h[0] = (_Float16)v0.x; h[1] = (_Float16)v0.y;
    h[2] = (_Float16)v0.z; h[3] = (_Float16)v0.w;
    h[4] = (_Float16)v1.x; h[5] = (_Float16)v1.y;
    h[6] = (_Float16)v1.z; h[7] = (_Float16)v1.w;
    return h;
}
__device__ __forceinline__ half8 load_afrag(const _Float16* A, int arow, int k0, int N) {
    return *(const half8*)(A + ((size_t)(k0 >> 4) * N + arow) * 16 + (k0 & 15));
}

template <typename AT>
__global__ __launch_bounds__(256, 2) void k_gemm(const AT* __restrict__ A,
                                                 const _Float16* __restrict__ Wt,
                                                 const float* __restrict__ dis,
                                                 __half* __restrict__ C, int N) {
    const int lane = threadIdx.x & 63;
    const int quad = lane >> 4;
    const int mc   = lane & 15;
    const int gw   = (blockIdx.x * 256 + threadIdx.x) >> 6;
    const int nw   = (gridDim.x * 256) >> 6;
    const int nstrips = (N + 15) >> 4;

    half8 b[8][4];
    #pragma unroll
    for (int j = 0; j < 8; j++)
        #pragma unroll
        for (int s = 0; s < 4; s++)
            b[j][s] = *(const half8*)(Wt + (size_t)(j * 16 + mc) * HID + s * 32 + quad * 8);

    int strip = gw;
    if (strip >= nstrips) return;

    half8 a[4];
    {
        int arow = strip * 16 + mc; if (arow >= N) arow = N - 1;
        #pragma unroll
        for (int s = 0; s < 4; s++) a[s] = load_afrag(A, arow, s * 32 + quad * 8, N);
    }

    for (; strip < nstrips; strip += nw) {
        const int row0 = strip * 16;
        const int next = strip + nw;
        half8 an[4];
        if (next < nstrips) {
            int arow = next * 16 + mc; if (arow >= N) arow = N - 1;
            #pragma unroll
            for (int s = 0; s < 4; s++) an[s] = load_afrag(A, arow, s * 32 + quad * 8, N);
        }
        floatx4 acc[8];
        #pragma unroll
        for (int j = 0; j < 8; j++) acc[j] = (floatx4){0.f, 0.f, 0.f, 0.f};
        #pragma unroll
        for (int s = 0; s < 4; s++)
            #pragma unroll
            for (int j = 0; j < 8; j++)
                acc[j] = __builtin_amdgcn_mfma_f32_16x16x32_f16(a[s], b[j][s], acc[j], 0, 0, 0);
        #pragma unroll
        for (int r = 0; r < 4; r++) {
            int gr = row0 + quad * 4 + r;
            if (gr < N) {
                float ds = dis[gr];
                #pragma unroll
                for (int j = 0; j < 8; j++)
                    C[((size_t)j * N + gr) * 16 + mc] = __float2half(ds * acc[j][r]);
            }
        }
        #pragma unroll
        for (int s = 0; s < 4; s++) a[s] = an[s];
    }
}

// ---------------- aggregation (8 slice passes, XCD-resident, LDS idx) -----
// pass = blockIdx & 7 == XCD id under round-robin dispatch. Block owns 32
// contiguous dsts -> contiguous csr range staged into LDS (coalesced nt).
// 8 lanes/dst: p = edge slot (4) x h = half slot (2). Lanes h=0,1 read the
// two float4 halves of the SAME edge -> one coalesced 32 B line request.
// Each lane owns 8 features; reduce over p with 2 shuffles.

__device__ __forceinline__ void add8(float* acc, float4 r) {
    __half2* h = (__half2*)&r;
    #pragma unroll
    for (int k = 0; k < 4; k++) {
        float2 v = __half22float2(h[k]);
        acc[2 * k]     += v.x;
        acc[2 * k + 1] += v.y;
    }
}

__global__ __launch_bounds__(256) void k_agg(const __half* __restrict__ T,
                                             const float* __restrict__ dis,
                                             const int* __restrict__ rowptr,
                                             const int* __restrict__ csr_src,
                                             const float* __restrict__ bias,
                                             __half* __restrict__ out, int N) {
    __shared__ int sidx[AGG_CHUNK];
    const int b    = blockIdx.x;
    const int pass = b & 7;            // == XCD id (round-robin dispatch)
    const int nbi  = b >> 3;
    const int t    = threadIdx.x;
    const int h    = t & 1;            // half slot (two float4 of one edge)
    const int p    = (t >> 1) & 3;     // edge slot
    const int n0   = nbi * 32;
    const int n    = n0 + (t >> 3);
    const bool act = (n < N);

    const int blk_e0 = rowptr[n0];
    const int blk_e1 = rowptr[(n0 + 32 < N) ? (n0 + 32) : N];

    const float4* T4 = (const float4*)(T + (size_t)pass * N * 16);

    float acc[8] = {};
    int mye = 0;
    int e   = 0;
    if (act) { e = rowptr[n] + p; mye = rowptr[n + 1]; }

    for (int cb = blk_e0; cb < blk_e1; cb += AGG_CHUNK) {
        const int cend = (cb + AGG_CHUNK < blk_e1) ? (cb + AGG_CHUNK) : blk_e1;
        __syncthreads();
        for (int i = cb + t; i < cend; i += 256)
            sidx[i - cb] = __builtin_nontemporal_load(csr_src + i);
        __syncthreads();
        const int bnd = (mye < cend) ? mye : cend;
        // 2-edge unroll: 2 coalesced 32 B requests in flight per lane-pair
        for (; e + 4 < bnd; e += 8) {
            int i0 = sidx[e - cb];
            int i1 = sidx[e + 4 - cb];
            float4 r0 = T4[(size_t)i0 * 2 + h];
            float4 r1 = T4[(size_t)i1 * 2 + h];
            add8(acc, r0);
            add8(acc, r1);
        }
        for (; e < bnd; e += 4) {
            int i0 = sidx[e - cb];
            add8(acc, T4[(size_t)i0 * 2 + h]);
        }
    }

    // reduce over edge slots p (lane bits 1,2)
    #pragma unroll
    for (int k = 0; k < 8; k++) {
        acc[k] += __shfl_xor(acc[k], 2, 64);
        acc[k] += __shfl_xor(acc[k], 4, 64);
    }

    if (act && p == 0) {
        add8(acc, T4[(size_t)n * 2 + h]);      // self-loop
        float dn = dis[n];
        half8 o;
        #pragma unroll
        for (int k = 0; k < 8; k++) {
            float v = fmaf(dn, acc[k], bias[pass * 16 + h * 8 + k]);
            o[k] = (_Float16)fmaxf(v, 0.f);
        }
        __builtin_nontemporal_store(
            o, (half8*)((_Float16*)out + ((size_t)pass * N + n) * 16 + h * 8));
    }
}

// ---------------- fused mean-pool + MLP head ----------------

__device__ __forceinline__ int lbound(const int* __restrict__ batch, int N, int g) {
    int lo = 0, hi = N;
    while (lo < hi) {
        int mid = (lo + hi) >> 1;
        if (batch[mid] < g) lo = mid + 1; else hi = mid;
    }
    return lo;
}

__global__ __launch_bounds__(256) void k_poolmlp(const __half* __restrict__ hbuf,
                                                 const int* __restrict__ batch,
                                                 const float* __restrict__ Wm0,
                                                 const float* __restrict__ bm0,
                                                 const float* __restrict__ Wm1,
                                                 const float* __restrict__ bm1,
                                                 float* __restrict__ out, int N) {
    __shared__ float red[2048];
    __shared__ float g[HID];
    const int gr = blockIdx.x, t = threadIdx.x;
    const int s = lbound(batch, N, gr), e = lbound(batch, N, gr + 1);

    const int rg = t >> 4, cl = t & 15;
    // 8-slice layout: chunk cl covers features [cl*8, cl*8+8) ->
    // slice cl>>1, in-slice offset (cl&1)*8, row stride 16.
    const _Float16* base = (const _Float16*)hbuf
        + (size_t)(cl >> 1) * N * 16 + (size_t)(cl & 1) * 8;
    float acc[8] = {};
    for (int r = s + rg; r < e; r += 16) {
        half8 v = *(const half8*)(base + (size_t)r * 16);
        #pragma unroll
        for (int k = 0; k < 8; k++) acc[k] += (float)v[k];
    }
    #pragma unroll
    for (int k = 0; k < 8; k++) red[t * 8 + k] = acc[k];
    __syncthreads();
    if (t < 128) {
        int cl2 = t >> 3, k = t & 7;
        float sm = 0.f;
        #pragma unroll
        for (int rg2 = 0; rg2 < 16; rg2++) sm += red[(rg2 * 16 + cl2) * 8 + k];
        int feat = (cl2 >> 1) * 16 + (cl2 & 1) * 8 + k;
        g[feat] = sm / fmaxf((float)(e - s), 1.f);
    }
    __syncthreads();

    const int j = t & 127, hh = t >> 7;
    float a = 0.f;
    for (int k = hh * 64; k < hh * 64 + 64; k++)
        a = fmaf(g[k], Wm0[(size_t)k * HID + j], a);
    red[hh * 128 + j] = a;
    __syncthreads();

    if (t < 128) {
        float h1 = fmaxf(bm0[j] + red[j] + red[128 + j], 0.f);
        float z = h1 * Wm1[j];
        #pragma unroll
        for (int off = 32; off > 0; off >>= 1) z += __shfl_xor(z, off, 64);
        if ((t & 63) == 0) red[1024 + (t >> 6)] = z;
    }
    __syncthreads();
    if (t == 0) out[gr] = red[1024] + red[1025] + bm1[0];
}

// ---------------- launch ----------------

extern "C" void kernel_launch(void* const* d_in, const int* in_sizes, int n_in,
                              void* d_out, int out_size, void* d_ws, size_t ws_size,
                              hipStream_t stream) {
    const float* x     = (const float*)d_in[0];
    const int*   ei    = (const int*)d_in[1];
    const int*   batch = (const int*)d_in[3];
    const float* W0 = (const float*)d_in[4],  *b0 = (const float*)d_in[5];
    const float* W1 = (const float*)d_in[6],  *b1 = (const float*)d_in[7];
    const float* W2 = (const float*)d_in[8],  *b2 = (const float*)d_in[9];
    const float* Wm0 = (const float*)d_in[10], *bm0 = (const float*)d_in[11];
    const float* Wm1 = (const float*)d_in[12], *bm1 = (const float*)d_in[13];

    const int N = in_sizes[0] / HID;
    const int E = in_sizes[1] / 2;
    const int nb = (N + NB_W - 1) >> NB_SHIFT;
    const int* row  = ei;
    const int* colI = ei + E;

    char* w = (char*)d_ws;
    auto carve = [&](size_t bytes) {
        void* p = (void*)w;
        w += (bytes + 255) & ~(size_t)255;
        return p;
    };
    int*      ibuf    = (int*)     carve(512 * 4);
    int*      bbase   = (int*)     carve(257 * 4);
    float*    dis     = (float*)   carve((size_t)N * 4);
    int*      rowptr  = (int*)     carve((size_t)(N + 1) * 4);
    unsigned* sorted  = (unsigned*)carve((size_t)E * 4);
    int*      csr_src = (int*)     carve((size_t)E * 4);
    _Float16* wth     = (_Float16*)carve((size_t)3 * HID * HID * 2);
    __half*   bufT    = (__half*)  carve((size_t)N * HID * 2);
    __half*   bufA    = (__half*)  carve((size_t)N * HID * 2);
    __half*   bufB    = (__half*)  carve((size_t)N * HID * 2);

    int* ghist = ibuf;
    int* bcur  = ibuf + 256;

    hipMemsetAsync(ibuf, 0, 512 * 4, stream);
    k_wprep  <<<48, 256, 0, stream>>>(W0, W1, W2, wth);
    k_hist   <<<512, 256, 0, stream>>>(colI, ghist, E, nb);
    k_bscan  <<<1, 256, 0, stream>>>(ghist, bbase, rowptr, N, E, nb);
    k_scatter<<<(E + EPB - 1) / EPB, 512, 0, stream>>>(row, colI, bbase, bcur, sorted, E);
    k_build  <<<nb, 512, 0, stream>>>(sorted, bbase, csr_src, rowptr, dis, N);

    dim3 gg(512);
    const int npb = (N + 31) / 32;          // dst-blocks per pass (32 dst/block)
    dim3 ga(8 * npb);                       // 8 slice passes, pass = blockIdx & 7

    k_gemm<float>    <<<gg, 256, 0, stream>>>(x, wth, dis, bufT, N);
    k_agg            <<<ga, 256, 0, stream>>>(bufT, dis, rowptr, csr_src, b0, bufA, N);
    k_gemm<_Float16> <<<gg, 256, 0, stream>>>((const _Float16*)bufA, wth + HID * HID, dis, bufT, N);
    k_agg            <<<ga, 256, 0, stream>>>(bufT, dis, rowptr, csr_src, b1, bufB, N);
    k_gemm<_Float16> <<<gg, 256, 0, stream>>>((const _Float16*)bufB, wth + 2 * HID * HID, dis, bufT, N);
    k_agg            <<<ga, 256, 0, stream>>>(bufT, dis, rowptr, csr_src, b2, bufA, N);

    k_poolmlp<<<NGR, 256, 0, stream>>>(bufA, batch, Wm0, bm0, Wm1, bm1, (float*)d_out, N);
}